// Round 12
// baseline (202.109 us; speedup 1.0000x reference)
//
#include <hip/hip_runtime.h>
#include <hip/hip_bf16.h>

// Problem constants
#define Bdim 2
#define Nseq 2048
#define Dmod 1024
#define Hn   16
#define HDim 64

#define XN  (Bdim * Nseq * Dmod)        // 4,194,304
#define WQN (3 * Dmod * Dmod)           // 3,145,728
#define WON (Dmod * Dmod)               // 1,048,576

typedef __attribute__((ext_vector_type(8))) __bf16 bf16x8;
typedef __attribute__((ext_vector_type(4))) __bf16 bf16x4;
typedef __attribute__((ext_vector_type(4))) float  floatx4;

__device__ __forceinline__ floatx4 mfma16(bf16x8 a, bf16x8 b, floatx4 c) {
    return __builtin_amdgcn_mfma_f32_16x16x32_bf16(a, b, c, 0, 0, 0);
}

// native v_exp_f32 computes 2^x
__device__ __forceinline__ float exp2v(float x) {
    return __builtin_amdgcn_exp2f(x);
}

// async global->LDS, 16 B per lane (GEMMs only; attn uses swizzled ds_write).
__device__ __forceinline__ void async_copy16(__bf16* l, const __bf16* g) {
    __builtin_amdgcn_global_load_lds(
        (const __attribute__((address_space(1))) void*)g,
        (__attribute__((address_space(3))) void*)l,
        16, 0, 0);
}

// ---------------------------------------------------------------------------
// Kernel 0: fp32 -> bf16 conversion of x, W_qkv, W_out into workspace.
// ---------------------------------------------------------------------------
__global__ __launch_bounds__(256) void convert_kernel(
    const float* __restrict__ x, const float* __restrict__ wq,
    const float* __restrict__ wo,
    __bf16* __restrict__ xb, __bf16* __restrict__ wqb, __bf16* __restrict__ wob)
{
    int i = (blockIdx.x * 256 + threadIdx.x) * 4;
    const float* src;
    __bf16* dst;
    int off;
    if (i < XN)            { src = x;  dst = xb;  off = i; }
    else if (i < XN + WQN) { src = wq; dst = wqb; off = i - XN; }
    else                   { src = wo; dst = wob; off = i - XN - WQN; }
    float4 v = *(const float4*)(src + off);
    bf16x4 o;
    o.x = (__bf16)v.x; o.y = (__bf16)v.y; o.z = (__bf16)v.z; o.w = (__bf16)v.w;
    *(bf16x4*)(dst + off) = o;
}

// ---------------------------------------------------------------------------
// Kernel 1: QKV projection — retiled BM=64 x BN=128 (was 128x128).
// Grid 64 m-tiles x 24 n-tiles = 1536 blocks = 6 blocks/CU (was 3/CU).
// Mirrors the proj retile that measured -4.5us: more resident blocks to
// hide the barrier drain. Wave = 32m x 64n (acc 2x4). LDS 12 KB.
// Epilogue scatters to Q [B,H,N,HD], K [B,H,N,HD], Vt [B,H,HD,N].
// ---------------------------------------------------------------------------
__global__ __launch_bounds__(256) void qkv_kernel(
    const __bf16* __restrict__ x, const __bf16* __restrict__ Wq,
    const float* __restrict__ bq,
    __bf16* __restrict__ qb, __bf16* __restrict__ kb, __bf16* __restrict__ vt)
{
    __shared__ __align__(16) __bf16 ldsA[64 * 32];
    __shared__ __align__(16) __bf16 ldsB[128 * 32];

    const int tid  = threadIdx.x;
    const int lane = tid & 63, l16 = lane & 15, quad = lane >> 4;
    const int wiw  = tid >> 6;
    const int wm   = wiw & 1, wn = wiw >> 1;

    const int bm = blockIdx.x & 63;             // 64 m-tiles (M=4096, BM=64)
    const int bn = blockIdx.x >> 6;             // 24 n-tiles (N=3072, BN=128)
    const int m0 = bm * 64, n0 = bn * 128;

    const int srow = tid >> 2;                  // staging row 0..63
    const int scol = (tid & 3) * 8;             // staging col {0,8,16,24}

    floatx4 z = {0.f, 0.f, 0.f, 0.f};
    floatx4 acc[2][4];
    #pragma unroll
    for (int mt = 0; mt < 2; ++mt)
        #pragma unroll
        for (int nt = 0; nt < 4; ++nt) acc[mt][nt] = z;

    const __bf16* ga = x  + (size_t)m0 * Dmod;
    const __bf16* gb = Wq + (size_t)n0 * Dmod;

    for (int k0 = 0; k0 < Dmod; k0 += 32) {
        async_copy16(&ldsA[srow * 32 + scol],        ga + (size_t)srow * Dmod + k0 + scol);
        async_copy16(&ldsB[srow * 32 + scol],        gb + (size_t)srow * Dmod + k0 + scol);
        async_copy16(&ldsB[(64 + srow) * 32 + scol], gb + (size_t)(64 + srow) * Dmod + k0 + scol);
        __syncthreads();

        bf16x8 af[2], bfr[4];
        #pragma unroll
        for (int mt = 0; mt < 2; ++mt)
            af[mt] = *(const bf16x8*)&ldsA[(wm * 32 + mt * 16 + l16) * 32 + quad * 8];
        #pragma unroll
        for (int nt = 0; nt < 4; ++nt)
            bfr[nt] = *(const bf16x8*)&ldsB[(wn * 64 + nt * 16 + l16) * 32 + quad * 8];
        #pragma unroll
        for (int mt = 0; mt < 2; ++mt)
            #pragma unroll
            for (int nt = 0; nt < 4; ++nt)
                acc[mt][nt] = mfma16(af[mt], bfr[nt], acc[mt][nt]);
        __syncthreads();
    }

    // Epilogue: wave n-base is 64-aligned -> single (which, head) per wave.
    const int nb    = n0 + wn * 64;
    const int which = nb >> 10;
    const int h     = (nb & 1023) >> 6;
    const int mw    = m0 + wm * 32;
    const int bi    = mw >> 11;
    const int pos0  = mw & (Nseq - 1);

    #pragma unroll
    for (int nt = 0; nt < 4; ++nt) {
        float bias = bq[nb + nt * 16 + l16];
        int hd = nt * 16 + l16;
        #pragma unroll
        for (int mt = 0; mt < 2; ++mt)
            #pragma unroll
            for (int i = 0; i < 4; ++i) {
                int pos = pos0 + mt * 16 + quad * 4 + i;
                __bf16 v = (__bf16)(acc[mt][nt][i] + bias);
                if (which == 0)
                    qb[((bi * Hn + h) * Nseq + pos) * HDim + hd] = v;
                else if (which == 1)
                    kb[((bi * Hn + h) * Nseq + pos) * HDim + hd] = v;
                else
                    vt[((bi * Hn + h) * HDim + hd) * Nseq + pos] = v;
            }
    }
}

// ---------------------------------------------------------------------------
// Kernel 2: causal flash attention, block-cooperative (proven R8 version —
// 49.4 us, VGPR 52, no scratch spill; 128-key variants R9/R10 spilled).
// Block = (bh, 64-query tile): 4 waves = 4 consecutive 16-q subtiles.
// K/V^T (64x64 each) staged once per 64-key tile, XOR block swizzle
// (phys 16B block = b ^ (row&7)) -> conflict-free ds_read_b128. Staging is
// register-prefetched one tile ahead. S^T = K·Q^T per-lane softmax.
// ---------------------------------------------------------------------------
__global__ __launch_bounds__(256, 4) void attn_kernel(
    const __bf16* __restrict__ qbuf, const __bf16* __restrict__ kbuf,
    const __bf16* __restrict__ vtbuf, __bf16* __restrict__ aout)
{
    __shared__ __align__(16) __bf16 ldsK[64 * 64];   // [key][d], swizzled
    __shared__ __align__(16) __bf16 ldsV[64 * 64];   // [d][key], swizzled
    __shared__ __align__(16) __bf16 ldsP[4][16 * 72];

    const int tid  = threadIdx.x;
    const int wiw  = tid >> 6;
    const int lane = tid & 63, l16 = lane & 15, quad = lane >> 4;
    const int b    = blockIdx.x;
    const int bh   = b & 31;
    const int qblk = 31 - (b >> 5);             // 64-q block index, heavy first
    const int q0   = qblk * 64 + wiw * 16;      // this wave's 16 queries

    const __bf16* qs = qbuf  + bh * Nseq * HDim;
    const __bf16* ks = kbuf  + bh * Nseq * HDim;
    const __bf16* vs = vtbuf + bh * HDim * Nseq;

    // staging coords: thread handles rows sr, sr+32; 16B block sb
    const int sr  = tid >> 3;                   // 0..31
    const int sb  = tid & 7;                    // 0..7
    const int swr = (sb ^ (sr & 7)) * 8;        // swizzled block offset (elems)
    const int wk0 = sr * 64 + swr;              // (sr+32)&7 == sr&7
    const int wk1 = (sr + 32) * 64 + swr;

    // Q as B-operand: lane l16 = q row, k = d = quad*8+j
    bf16x8 qf0 = *(const bf16x8*)(qs + (q0 + l16) * HDim + quad * 8);
    bf16x8 qf1 = *(const bf16x8*)(qs + (q0 + l16) * HDim + 32 + quad * 8);

    floatx4 z = {0.f, 0.f, 0.f, 0.f};
    floatx4 o[4];
    #pragma unroll
    for (int s = 0; s < 4; ++s) o[s] = z;
    float m_i = -1e30f, l_i = 0.f;              // per-lane: q = q0 + l16

    const float C   = 0.125f * 1.44269504f;     // scale * log2(e)
    const int   nkt = qblk + 1;                 // 64-key tiles (uniform in block)
    __bf16* myp = ldsP[wiw];
    const int swz = l16 & 7;                    // read-side swizzle (row&7)

    // prefetch tile 0 into registers
    float4 rk0 = *(const float4*)(ks + (size_t)sr * HDim + sb * 8);
    float4 rk1 = *(const float4*)(ks + (size_t)(sr + 32) * HDim + sb * 8);
    float4 rv0 = *(const float4*)(vs + (size_t)sr * Nseq + sb * 8);
    float4 rv1 = *(const float4*)(vs + (size_t)(sr + 32) * Nseq + sb * 8);

    for (int kt = 0; kt < nkt; ++kt) {
        // issue next tile's global loads first (in flight during compute)
        float4 nk0 = {}, nk1 = {}, nv0 = {}, nv1 = {};
        if (kt + 1 < nkt) {
            const int k0n = (kt + 1) * 64;
            nk0 = *(const float4*)(ks + (size_t)(k0n + sr) * HDim + sb * 8);
            nk1 = *(const float4*)(ks + (size_t)(k0n + sr + 32) * HDim + sb * 8);
            nv0 = *(const float4*)(vs + (size_t)sr * Nseq + k0n + sb * 8);
            nv1 = *(const float4*)(vs + (size_t)(sr + 32) * Nseq + k0n + sb * 8);
        }

        // write current tile to LDS (swizzled)
        *(float4*)&ldsK[wk0] = rk0;
        *(float4*)&ldsK[wk1] = rk1;
        *(float4*)&ldsV[wk0] = rv0;
        *(float4*)&ldsV[wk1] = rv1;
        __syncthreads();

        const bool last = (kt == nkt - 1);

        // S^T: 4 subtiles of 16 keys. A=K (m=key), B=Q (n=q).
        floatx4 st[4];
        #pragma unroll
        for (int t = 0; t < 4; ++t) {
            const __bf16* kr = &ldsK[(t * 16 + l16) * 64];
            bf16x8 kf0 = *(const bf16x8*)(kr + ((quad ^ swz) * 8));
            bf16x8 kf1 = *(const bf16x8*)(kr + (((quad + 4) ^ swz) * 8));
            st[t] = mfma16(kf0, qf0, z);
            st[t] = mfma16(kf1, qf1, st[t]);
        }

        // scores (log2 domain); lane holds keys {16t+quad*4+i} for q=q0+l16
        float a[16];
        #pragma unroll
        for (int t = 0; t < 4; ++t)
            #pragma unroll
            for (int i = 0; i < 4; ++i) {
                float v = st[t][i] * C;
                if (last) {
                    int kidx = t * 16 + quad * 4 + i;      // key - k0
                    v = (kidx <= wiw * 16 + l16) ? v : -1e30f;
                }
                a[t * 4 + i] = v;
            }

        // row max: depth-4 tree + 2 cross-quad shuffles
        float mA = fmaxf(fmaxf(a[0], a[1]),  fmaxf(a[2], a[3]));
        float mB = fmaxf(fmaxf(a[4], a[5]),  fmaxf(a[6], a[7]));
        float mC = fmaxf(fmaxf(a[8], a[9]),  fmaxf(a[10], a[11]));
        float mD = fmaxf(fmaxf(a[12], a[13]), fmaxf(a[14], a[15]));
        float mx = fmaxf(fmaxf(mA, mB), fmaxf(mC, mD));
        mx = fmaxf(mx, __shfl_xor(mx, 16));
        mx = fmaxf(mx, __shfl_xor(mx, 32));

        float mn    = fmaxf(m_i, mx);
        float alpha = exp2v(m_i - mn);

        float p[16];
        #pragma unroll
        for (int j = 0; j < 16; ++j) p[j] = exp2v(a[j] - mn);
        float sA = (p[0] + p[1]) + (p[2] + p[3]);
        float sB = (p[4] + p[5]) + (p[6] + p[7]);
        float sC = (p[8] + p[9]) + (p[10] + p[11]);
        float sD = (p[12] + p[13]) + (p[14] + p[15]);
        float rs = (sA + sB) + (sC + sD);
        rs += __shfl_xor(rs, 16);
        rs += __shfl_xor(rs, 32);
        l_i = l_i * alpha + rs;
        m_i = mn;

        #pragma unroll
        for (int s = 0; s < 4; ++s)
            #pragma unroll
            for (int i = 0; i < 4; ++i) o[s][i] *= alpha;

        // P: C-layout -> LDS -> B-layout (per-wave region, stride 72)
        #pragma unroll
        for (int t = 0; t < 4; ++t) {
            bf16x4 pk;
            pk.x = (__bf16)p[t * 4 + 0]; pk.y = (__bf16)p[t * 4 + 1];
            pk.z = (__bf16)p[t * 4 + 2]; pk.w = (__bf16)p[t * 4 + 3];
            *(bf16x4*)(myp + l16 * 72 + t * 16 + quad * 4) = pk;
        }
        asm volatile("s_waitcnt lgkmcnt(0)" ::: "memory");
        bf16x8 pf0 = *(const bf16x8*)(myp + l16 * 72 + quad * 8);
        bf16x8 pf1 = *(const bf16x8*)(myp + l16 * 72 + 32 + quad * 8);

        // O^T += V^T P^T : A=V^T (m=d, k=key) from LDS (swizzled)
        #pragma unroll
        for (int s = 0; s < 4; ++s) {
            const __bf16* vr = &ldsV[(s * 16 + l16) * 64];
            bf16x8 vf0 = *(const bf16x8*)(vr + ((quad ^ swz) * 8));
            bf16x8 vf1 = *(const bf16x8*)(vr + (((quad + 4) ^ swz) * 8));
            o[s] = mfma16(vf0, pf0, o[s]);
            o[s] = mfma16(vf1, pf1, o[s]);
        }
        __syncthreads();                        // all waves done with K/V tile

        rk0 = nk0; rk1 = nk1; rv0 = nv0; rv1 = nv1;
    }

    // Epilogue: O^T tile s: row = d = s*16+quad*4+i, col = q = q0+l16
    const float inv = 1.0f / l_i;
    const int bi = bh >> 4, h = bh & 15;
    #pragma unroll
    for (int s = 0; s < 4; ++s) {
        bf16x4 ov;
        ov.x = (__bf16)(o[s][0] * inv); ov.y = (__bf16)(o[s][1] * inv);
        ov.z = (__bf16)(o[s][2] * inv); ov.w = (__bf16)(o[s][3] * inv);
        *(bf16x4*)(aout + ((size_t)(bi * Nseq + q0 + l16)) * Dmod
                   + h * 64 + s * 16 + quad * 4) = ov;
    }
}

// ---------------------------------------------------------------------------
// Kernel 3: output projection — BM=64 x BN=128 retile (measured -4.5us).
// Grid 64 m-tiles x 8 n-tiles = 512 blocks = 2 blocks/CU.
// ---------------------------------------------------------------------------
__global__ __launch_bounds__(256) void proj_kernel(
    const __bf16* __restrict__ ao, const __bf16* __restrict__ Wo,
    const float* __restrict__ bo, float* __restrict__ out)
{
    __shared__ __align__(16) __bf16 ldsA[64 * 32];
    __shared__ __align__(16) __bf16 ldsB[128 * 32];

    const int tid  = threadIdx.x;
    const int lane = tid & 63, l16 = lane & 15, quad = lane >> 4;
    const int wiw  = tid >> 6;
    const int wm   = wiw & 1, wn = wiw >> 1;

    const int bm = blockIdx.x & 63;             // 64 m-tiles (M=4096, BM=64)
    const int bn = blockIdx.x >> 6;             // 8 n-tiles (N=1024, BN=128)
    const int m0 = bm * 64, n0 = bn * 128;

    const int srow = tid >> 2;                  // 0..63
    const int scol = (tid & 3) * 8;             // {0,8,16,24}

    floatx4 z = {0.f, 0.f, 0.f, 0.f};
    floatx4 acc[2][4];
    #pragma unroll
    for (int mt = 0; mt < 2; ++mt)
        #pragma unroll
        for (int nt = 0; nt < 4; ++nt) acc[mt][nt] = z;

    const __bf16* ga = ao + (size_t)m0 * Dmod;
    const __bf16* gb = Wo + (size_t)n0 * Dmod;

    for (int k0 = 0; k0 < Dmod; k0 += 32) {
        async_copy16(&ldsA[srow * 32 + scol],        ga + (size_t)srow * Dmod + k0 + scol);
        async_copy16(&ldsB[srow * 32 + scol],        gb + (size_t)srow * Dmod + k0 + scol);
        async_copy16(&ldsB[(64 + srow) * 32 + scol], gb + (size_t)(64 + srow) * Dmod + k0 + scol);
        __syncthreads();

        bf16x8 af[2], bfr[4];
        #pragma unroll
        for (int mt = 0; mt < 2; ++mt)
            af[mt] = *(const bf16x8*)&ldsA[(wm * 32 + mt * 16 + l16) * 32 + quad * 8];
        #pragma unroll
        for (int nt = 0; nt < 4; ++nt)
            bfr[nt] = *(const bf16x8*)&ldsB[(wn * 64 + nt * 16 + l16) * 32 + quad * 8];
        #pragma unroll
        for (int mt = 0; mt < 2; ++mt)
            #pragma unroll
            for (int nt = 0; nt < 4; ++nt)
                acc[mt][nt] = mfma16(af[mt], bfr[nt], acc[mt][nt]);
        __syncthreads();
    }

    const int nb = n0 + wn * 64;
    const int mw = m0 + wm * 32;
    #pragma unroll
    for (int nt = 0; nt < 4; ++nt) {
        float bias = bo[nb + nt * 16 + l16];
        #pragma unroll
        for (int mt = 0; mt < 2; ++mt)
            #pragma unroll
            for (int i = 0; i < 4; ++i) {
                int m = mw + mt * 16 + quad * 4 + i;
                out[(size_t)m * Dmod + nb + nt * 16 + l16] = acc[mt][nt][i] + bias;
            }
    }
}

// ---------------------------------------------------------------------------
extern "C" void kernel_launch(void* const* d_in, const int* in_sizes, int n_in,
                              void* d_out, int out_size, void* d_ws, size_t ws_size,
                              hipStream_t stream) {
    const float* x  = (const float*)d_in[0];
    const float* Wq = (const float*)d_in[1];
    const float* bq = (const float*)d_in[2];
    const float* Wo = (const float*)d_in[3];
    const float* bo = (const float*)d_in[4];
    float* out = (float*)d_out;

    __bf16* ws  = (__bf16*)d_ws;
    __bf16* xb  = ws;
    __bf16* wqb = ws + (size_t)XN;
    __bf16* wob = wqb + (size_t)WQN;
    __bf16* qb  = wob + (size_t)WON;
    const size_t SZ = (size_t)Bdim * Hn * Nseq * HDim;
    __bf16* kb  = qb + SZ;
    __bf16* vt  = kb + SZ;
    __bf16* ao  = vt + SZ;

    convert_kernel<<<dim3(8192), dim3(256), 0, stream>>>(x, Wq, Wo, xb, wqb, wob);
    // 64 m-tiles x 24 n-tiles = 1536 blocks (6 blocks/CU)
    qkv_kernel<<<dim3(1536), dim3(256), 0, stream>>>(xb, wqb, bq, qb, kb, vt);
    // 32 bh x 32 q-blocks = 1024 blocks, 4 waves each (block-cooperative)
    attn_kernel<<<dim3(1024), dim3(256), 0, stream>>>(qb, kb, vt, ao);
    // 64 m-tiles x 8 n-tiles = 512 blocks (2 blocks/CU)
    proj_kernel<<<dim3(512), dim3(256), 0, stream>>>(ao, wob, bo, out);
}

// Round 13
// 183.184 us; speedup vs baseline: 1.1033x; 1.1033x over previous
//
#include <hip/hip_runtime.h>
#include <hip/hip_bf16.h>

// Problem constants
#define Bdim 2
#define Nseq 2048
#define Dmod 1024
#define Hn   16
#define HDim 64

#define XN  (Bdim * Nseq * Dmod)        // 4,194,304
#define WQN (3 * Dmod * Dmod)           // 3,145,728
#define WON (Dmod * Dmod)               // 1,048,576

typedef __attribute__((ext_vector_type(8))) __bf16 bf16x8;
typedef __attribute__((ext_vector_type(4))) __bf16 bf16x4;
typedef __attribute__((ext_vector_type(4))) float  floatx4;

__device__ __forceinline__ floatx4 mfma16(bf16x8 a, bf16x8 b, floatx4 c) {
    return __builtin_amdgcn_mfma_f32_16x16x32_bf16(a, b, c, 0, 0, 0);
}

// native v_exp_f32 computes 2^x
__device__ __forceinline__ float exp2v(float x) {
    return __builtin_amdgcn_exp2f(x);
}

// async global->LDS, 16 B per lane (GEMMs only; attn uses swizzled ds_write).
__device__ __forceinline__ void async_copy16(__bf16* l, const __bf16* g) {
    __builtin_amdgcn_global_load_lds(
        (const __attribute__((address_space(1))) void*)g,
        (__attribute__((address_space(3))) void*)l,
        16, 0, 0);
}

// ---------------------------------------------------------------------------
// Kernel 0: fp32 -> bf16 conversion. 8 elems/thread: 2x float4 load (32 B)
// + 1x bf16x8 store (16 B/lane = coalescing sweet spot; old bf16x4 was 8 B).
// All tensor sizes are multiples of 8 -> no tensor straddle within a thread.
// ---------------------------------------------------------------------------
__global__ __launch_bounds__(256) void convert_kernel(
    const float* __restrict__ x, const float* __restrict__ wq,
    const float* __restrict__ wo,
    __bf16* __restrict__ xb, __bf16* __restrict__ wqb, __bf16* __restrict__ wob)
{
    int i = (blockIdx.x * 256 + threadIdx.x) * 8;
    const float* src;
    __bf16* dst;
    int off;
    if (i < XN)            { src = x;  dst = xb;  off = i; }
    else if (i < XN + WQN) { src = wq; dst = wqb; off = i - XN; }
    else                   { src = wo; dst = wob; off = i - XN - WQN; }
    float4 v0 = *(const float4*)(src + off);
    float4 v1 = *(const float4*)(src + off + 4);
    bf16x8 o;
    o[0] = (__bf16)v0.x; o[1] = (__bf16)v0.y; o[2] = (__bf16)v0.z; o[3] = (__bf16)v0.w;
    o[4] = (__bf16)v1.x; o[5] = (__bf16)v1.y; o[6] = (__bf16)v1.z; o[7] = (__bf16)v1.w;
    *(bf16x8*)(dst + off) = o;
}

// ---------------------------------------------------------------------------
// Kernel 1: QKV projection — m97-style 128x128 LDS-staged GEMM (reverted to
// the proven R11 version; the BM=64 retile regressed: 2x4-acc waves halve
// MFMA-per-staged-byte and double barrier crossings — 64-tile = 343 TF vs
// 128-tile = 912 TF in the measured tile-space).
// ---------------------------------------------------------------------------
__global__ __launch_bounds__(256) void qkv_kernel(
    const __bf16* __restrict__ x, const __bf16* __restrict__ Wq,
    const float* __restrict__ bq,
    __bf16* __restrict__ qb, __bf16* __restrict__ kb, __bf16* __restrict__ vt)
{
    __shared__ __align__(16) __bf16 ldsA[128 * 32];
    __shared__ __align__(16) __bf16 ldsB[128 * 32];

    const int tid  = threadIdx.x;
    const int lane = tid & 63, l16 = lane & 15, quad = lane >> 4;
    const int wiw  = tid >> 6;
    const int wm   = wiw & 1, wn = wiw >> 1;

    const int bm = blockIdx.x & 31;             // 32 m-tiles (M=4096)
    const int bn = blockIdx.x >> 5;             // 24 n-tiles (N=3072)
    const int m0 = bm * 128, n0 = bn * 128;

    const int srow = tid >> 2;                  // staging row 0..63
    const int scol = (tid & 3) * 8;             // staging col {0,8,16,24}

    floatx4 z = {0.f, 0.f, 0.f, 0.f};
    floatx4 acc[4][4];
    #pragma unroll
    for (int mt = 0; mt < 4; ++mt)
        #pragma unroll
        for (int nt = 0; nt < 4; ++nt) acc[mt][nt] = z;

    const __bf16* ga = x  + (size_t)m0 * Dmod;
    const __bf16* gb = Wq + (size_t)n0 * Dmod;

    for (int k0 = 0; k0 < Dmod; k0 += 32) {
        async_copy16(&ldsA[srow * 32 + scol],        ga + (size_t)srow * Dmod + k0 + scol);
        async_copy16(&ldsA[(64 + srow) * 32 + scol], ga + (size_t)(64 + srow) * Dmod + k0 + scol);
        async_copy16(&ldsB[srow * 32 + scol],        gb + (size_t)srow * Dmod + k0 + scol);
        async_copy16(&ldsB[(64 + srow) * 32 + scol], gb + (size_t)(64 + srow) * Dmod + k0 + scol);
        __syncthreads();

        bf16x8 af[4], bfr[4];
        #pragma unroll
        for (int mt = 0; mt < 4; ++mt)
            af[mt] = *(const bf16x8*)&ldsA[(wm * 64 + mt * 16 + l16) * 32 + quad * 8];
        #pragma unroll
        for (int nt = 0; nt < 4; ++nt)
            bfr[nt] = *(const bf16x8*)&ldsB[(wn * 64 + nt * 16 + l16) * 32 + quad * 8];
        #pragma unroll
        for (int mt = 0; mt < 4; ++mt)
            #pragma unroll
            for (int nt = 0; nt < 4; ++nt)
                acc[mt][nt] = mfma16(af[mt], bfr[nt], acc[mt][nt]);
        __syncthreads();
    }

    const int nb    = n0 + wn * 64;
    const int which = nb >> 10;
    const int h     = (nb & 1023) >> 6;
    const int mw    = m0 + wm * 64;
    const int bi    = mw >> 11;
    const int pos0  = mw & (Nseq - 1);

    #pragma unroll
    for (int nt = 0; nt < 4; ++nt) {
        float bias = bq[nb + nt * 16 + l16];
        int hd = nt * 16 + l16;
        #pragma unroll
        for (int mt = 0; mt < 4; ++mt)
            #pragma unroll
            for (int i = 0; i < 4; ++i) {
                int pos = pos0 + mt * 16 + quad * 4 + i;
                __bf16 v = (__bf16)(acc[mt][nt][i] + bias);
                if (which == 0)
                    qb[((bi * Hn + h) * Nseq + pos) * HDim + hd] = v;
                else if (which == 1)
                    kb[((bi * Hn + h) * Nseq + pos) * HDim + hd] = v;
                else
                    vt[((bi * Hn + h) * HDim + hd) * Nseq + pos] = v;
            }
    }
}

// ---------------------------------------------------------------------------
// Kernel 2: causal flash attention, block-cooperative (proven R8 version —
// 49.4 us, VGPR 52, no scratch spill; 128-key variants R9/R10 spilled).
// ---------------------------------------------------------------------------
__global__ __launch_bounds__(256, 4) void attn_kernel(
    const __bf16* __restrict__ qbuf, const __bf16* __restrict__ kbuf,
    const __bf16* __restrict__ vtbuf, __bf16* __restrict__ aout)
{
    __shared__ __align__(16) __bf16 ldsK[64 * 64];   // [key][d], swizzled
    __shared__ __align__(16) __bf16 ldsV[64 * 64];   // [d][key], swizzled
    __shared__ __align__(16) __bf16 ldsP[4][16 * 72];

    const int tid  = threadIdx.x;
    const int wiw  = tid >> 6;
    const int lane = tid & 63, l16 = lane & 15, quad = lane >> 4;
    const int b    = blockIdx.x;
    const int bh   = b & 31;
    const int qblk = 31 - (b >> 5);             // 64-q block index, heavy first
    const int q0   = qblk * 64 + wiw * 16;      // this wave's 16 queries

    const __bf16* qs = qbuf  + bh * Nseq * HDim;
    const __bf16* ks = kbuf  + bh * Nseq * HDim;
    const __bf16* vs = vtbuf + bh * HDim * Nseq;

    // staging coords: thread handles rows sr, sr+32; 16B block sb
    const int sr  = tid >> 3;                   // 0..31
    const int sb  = tid & 7;                    // 0..7
    const int swr = (sb ^ (sr & 7)) * 8;        // swizzled block offset (elems)
    const int wk0 = sr * 64 + swr;              // (sr+32)&7 == sr&7
    const int wk1 = (sr + 32) * 64 + swr;

    // Q as B-operand: lane l16 = q row, k = d = quad*8+j
    bf16x8 qf0 = *(const bf16x8*)(qs + (q0 + l16) * HDim + quad * 8);
    bf16x8 qf1 = *(const bf16x8*)(qs + (q0 + l16) * HDim + 32 + quad * 8);

    floatx4 z = {0.f, 0.f, 0.f, 0.f};
    floatx4 o[4];
    #pragma unroll
    for (int s = 0; s < 4; ++s) o[s] = z;
    float m_i = -1e30f, l_i = 0.f;              // per-lane: q = q0 + l16

    const float C   = 0.125f * 1.44269504f;     // scale * log2(e)
    const int   nkt = qblk + 1;                 // 64-key tiles (uniform in block)
    __bf16* myp = ldsP[wiw];
    const int swz = l16 & 7;                    // read-side swizzle (row&7)

    // prefetch tile 0 into registers
    float4 rk0 = *(const float4*)(ks + (size_t)sr * HDim + sb * 8);
    float4 rk1 = *(const float4*)(ks + (size_t)(sr + 32) * HDim + sb * 8);
    float4 rv0 = *(const float4*)(vs + (size_t)sr * Nseq + sb * 8);
    float4 rv1 = *(const float4*)(vs + (size_t)(sr + 32) * Nseq + sb * 8);

    for (int kt = 0; kt < nkt; ++kt) {
        // issue next tile's global loads first (in flight during compute)
        float4 nk0 = {}, nk1 = {}, nv0 = {}, nv1 = {};
        if (kt + 1 < nkt) {
            const int k0n = (kt + 1) * 64;
            nk0 = *(const float4*)(ks + (size_t)(k0n + sr) * HDim + sb * 8);
            nk1 = *(const float4*)(ks + (size_t)(k0n + sr + 32) * HDim + sb * 8);
            nv0 = *(const float4*)(vs + (size_t)sr * Nseq + k0n + sb * 8);
            nv1 = *(const float4*)(vs + (size_t)(sr + 32) * Nseq + k0n + sb * 8);
        }

        // write current tile to LDS (swizzled)
        *(float4*)&ldsK[wk0] = rk0;
        *(float4*)&ldsK[wk1] = rk1;
        *(float4*)&ldsV[wk0] = rv0;
        *(float4*)&ldsV[wk1] = rv1;
        __syncthreads();

        const bool last = (kt == nkt - 1);

        // S^T: 4 subtiles of 16 keys. A=K (m=key), B=Q (n=q).
        floatx4 st[4];
        #pragma unroll
        for (int t = 0; t < 4; ++t) {
            const __bf16* kr = &ldsK[(t * 16 + l16) * 64];
            bf16x8 kf0 = *(const bf16x8*)(kr + ((quad ^ swz) * 8));
            bf16x8 kf1 = *(const bf16x8*)(kr + (((quad + 4) ^ swz) * 8));
            st[t] = mfma16(kf0, qf0, z);
            st[t] = mfma16(kf1, qf1, st[t]);
        }

        // scores (log2 domain); lane holds keys {16t+quad*4+i} for q=q0+l16
        float a[16];
        #pragma unroll
        for (int t = 0; t < 4; ++t)
            #pragma unroll
            for (int i = 0; i < 4; ++i) {
                float v = st[t][i] * C;
                if (last) {
                    int kidx = t * 16 + quad * 4 + i;      // key - k0
                    v = (kidx <= wiw * 16 + l16) ? v : -1e30f;
                }
                a[t * 4 + i] = v;
            }

        // row max: depth-4 tree + 2 cross-quad shuffles
        float mA = fmaxf(fmaxf(a[0], a[1]),  fmaxf(a[2], a[3]));
        float mB = fmaxf(fmaxf(a[4], a[5]),  fmaxf(a[6], a[7]));
        float mC = fmaxf(fmaxf(a[8], a[9]),  fmaxf(a[10], a[11]));
        float mD = fmaxf(fmaxf(a[12], a[13]), fmaxf(a[14], a[15]));
        float mx = fmaxf(fmaxf(mA, mB), fmaxf(mC, mD));
        mx = fmaxf(mx, __shfl_xor(mx, 16));
        mx = fmaxf(mx, __shfl_xor(mx, 32));

        float mn    = fmaxf(m_i, mx);
        float alpha = exp2v(m_i - mn);

        float p[16];
        #pragma unroll
        for (int j = 0; j < 16; ++j) p[j] = exp2v(a[j] - mn);
        float sA = (p[0] + p[1]) + (p[2] + p[3]);
        float sB = (p[4] + p[5]) + (p[6] + p[7]);
        float sC = (p[8] + p[9]) + (p[10] + p[11]);
        float sD = (p[12] + p[13]) + (p[14] + p[15]);
        float rs = (sA + sB) + (sC + sD);
        rs += __shfl_xor(rs, 16);
        rs += __shfl_xor(rs, 32);
        l_i = l_i * alpha + rs;
        m_i = mn;

        #pragma unroll
        for (int s = 0; s < 4; ++s)
            #pragma unroll
            for (int i = 0; i < 4; ++i) o[s][i] *= alpha;

        // P: C-layout -> LDS -> B-layout (per-wave region, stride 72)
        #pragma unroll
        for (int t = 0; t < 4; ++t) {
            bf16x4 pk;
            pk.x = (__bf16)p[t * 4 + 0]; pk.y = (__bf16)p[t * 4 + 1];
            pk.z = (__bf16)p[t * 4 + 2]; pk.w = (__bf16)p[t * 4 + 3];
            *(bf16x4*)(myp + l16 * 72 + t * 16 + quad * 4) = pk;
        }
        asm volatile("s_waitcnt lgkmcnt(0)" ::: "memory");
        bf16x8 pf0 = *(const bf16x8*)(myp + l16 * 72 + quad * 8);
        bf16x8 pf1 = *(const bf16x8*)(myp + l16 * 72 + 32 + quad * 8);

        // O^T += V^T P^T : A=V^T (m=d, k=key) from LDS (swizzled)
        #pragma unroll
        for (int s = 0; s < 4; ++s) {
            const __bf16* vr = &ldsV[(s * 16 + l16) * 64];
            bf16x8 vf0 = *(const bf16x8*)(vr + ((quad ^ swz) * 8));
            bf16x8 vf1 = *(const bf16x8*)(vr + (((quad + 4) ^ swz) * 8));
            o[s] = mfma16(vf0, pf0, o[s]);
            o[s] = mfma16(vf1, pf1, o[s]);
        }
        __syncthreads();                        // all waves done with K/V tile

        rk0 = nk0; rk1 = nk1; rv0 = nv0; rv1 = nv1;
    }

    // Epilogue: O^T tile s: row = d = s*16+quad*4+i, col = q = q0+l16
    const float inv = 1.0f / l_i;
    const int bi = bh >> 4, h = bh & 15;
    #pragma unroll
    for (int s = 0; s < 4; ++s) {
        bf16x4 ov;
        ov.x = (__bf16)(o[s][0] * inv); ov.y = (__bf16)(o[s][1] * inv);
        ov.z = (__bf16)(o[s][2] * inv); ov.w = (__bf16)(o[s][3] * inv);
        *(bf16x4*)(aout + ((size_t)(bi * Nseq + q0 + l16)) * Dmod
                   + h * 64 + s * 16 + quad * 4) = ov;
    }
}

// ---------------------------------------------------------------------------
// Kernel 3: output projection — BM=64 x BN=128 retile (measured -4.5us).
// Grid 64 m-tiles x 8 n-tiles = 512 blocks = 2 blocks/CU.
// ---------------------------------------------------------------------------
__global__ __launch_bounds__(256) void proj_kernel(
    const __bf16* __restrict__ ao, const __bf16* __restrict__ Wo,
    const float* __restrict__ bo, float* __restrict__ out)
{
    __shared__ __align__(16) __bf16 ldsA[64 * 32];
    __shared__ __align__(16) __bf16 ldsB[128 * 32];

    const int tid  = threadIdx.x;
    const int lane = tid & 63, l16 = lane & 15, quad = lane >> 4;
    const int wiw  = tid >> 6;
    const int wm   = wiw & 1, wn = wiw >> 1;

    const int bm = blockIdx.x & 63;             // 64 m-tiles (M=4096, BM=64)
    const int bn = blockIdx.x >> 6;             // 8 n-tiles (N=1024, BN=128)
    const int m0 = bm * 64, n0 = bn * 128;

    const int srow = tid >> 2;                  // 0..63
    const int scol = (tid & 3) * 8;             // {0,8,16,24}

    floatx4 z = {0.f, 0.f, 0.f, 0.f};
    floatx4 acc[2][4];
    #pragma unroll
    for (int mt = 0; mt < 2; ++mt)
        #pragma unroll
        for (int nt = 0; nt < 4; ++nt) acc[mt][nt] = z;

    const __bf16* ga = ao + (size_t)m0 * Dmod;
    const __bf16* gb = Wo + (size_t)n0 * Dmod;

    for (int k0 = 0; k0 < Dmod; k0 += 32) {
        async_copy16(&ldsA[srow * 32 + scol],        ga + (size_t)srow * Dmod + k0 + scol);
        async_copy16(&ldsB[srow * 32 + scol],        gb + (size_t)srow * Dmod + k0 + scol);
        async_copy16(&ldsB[(64 + srow) * 32 + scol], gb + (size_t)(64 + srow) * Dmod + k0 + scol);
        __syncthreads();

        bf16x8 af[2], bfr[4];
        #pragma unroll
        for (int mt = 0; mt < 2; ++mt)
            af[mt] = *(const bf16x8*)&ldsA[(wm * 32 + mt * 16 + l16) * 32 + quad * 8];
        #pragma unroll
        for (int nt = 0; nt < 4; ++nt)
            bfr[nt] = *(const bf16x8*)&ldsB[(wn * 64 + nt * 16 + l16) * 32 + quad * 8];
        #pragma unroll
        for (int mt = 0; mt < 2; ++mt)
            #pragma unroll
            for (int nt = 0; nt < 4; ++nt)
                acc[mt][nt] = mfma16(af[mt], bfr[nt], acc[mt][nt]);
        __syncthreads();
    }

    const int nb = n0 + wn * 64;
    const int mw = m0 + wm * 32;
    #pragma unroll
    for (int nt = 0; nt < 4; ++nt) {
        float bias = bo[nb + nt * 16 + l16];
        #pragma unroll
        for (int mt = 0; mt < 2; ++mt)
            #pragma unroll
            for (int i = 0; i < 4; ++i) {
                int m = mw + mt * 16 + quad * 4 + i;
                out[(size_t)m * Dmod + nb + nt * 16 + l16] = acc[mt][nt][i] + bias;
            }
    }
}

// ---------------------------------------------------------------------------
extern "C" void kernel_launch(void* const* d_in, const int* in_sizes, int n_in,
                              void* d_out, int out_size, void* d_ws, size_t ws_size,
                              hipStream_t stream) {
    const float* x  = (const float*)d_in[0];
    const float* Wq = (const float*)d_in[1];
    const float* bq = (const float*)d_in[2];
    const float* Wo = (const float*)d_in[3];
    const float* bo = (const float*)d_in[4];
    float* out = (float*)d_out;

    __bf16* ws  = (__bf16*)d_ws;
    __bf16* xb  = ws;
    __bf16* wqb = ws + (size_t)XN;
    __bf16* wob = wqb + (size_t)WQN;
    __bf16* qb  = wob + (size_t)WON;
    const size_t SZ = (size_t)Bdim * Hn * Nseq * HDim;
    __bf16* kb  = qb + SZ;
    __bf16* vt  = kb + SZ;
    __bf16* ao  = vt + SZ;

    // 8.38M elems / 8 per thread / 256 = 4096 blocks
    convert_kernel<<<dim3(4096), dim3(256), 0, stream>>>(x, Wq, Wo, xb, wqb, wob);
    // 32 m-tiles x 24 n-tiles = 768 blocks (proven 128x128 tile)
    qkv_kernel<<<dim3(768), dim3(256), 0, stream>>>(xb, wqb, bq, qb, kb, vt);
    // 32 bh x 32 q-blocks = 1024 blocks, 4 waves each (block-cooperative)
    attn_kernel<<<dim3(1024), dim3(256), 0, stream>>>(qb, kb, vt, ao);
    // 64 m-tiles x 8 n-tiles = 512 blocks (2 blocks/CU)
    proj_kernel<<<dim3(512), dim3(256), 0, stream>>>(ao, wob, bo, out);
}